// Round 8
// baseline (184.114 us; speedup 1.0000x reference)
//
#include <hip/hip_runtime.h>
#include <cstdint>

// MHA fwd: B=4, S=2048, D=1024, H=16, HD=64. fp32 in/out.
// Round 8: GEMMs rebuilt as 256x128-tile, 8-wave, 3-buffer-ring deep pipeline
// (prefetch distance 2 K-tiles, counted vmcnt(8), 4 phases/K-tile, 1 barrier/phase,
// XOR-swizzled LDS, setprio around MFMA). QKV grid 768 = 3 exact rounds,
// O grid 256 = 1 round. Attn v6 unchanged.

typedef __bf16 bf16x8 __attribute__((ext_vector_type(8)));
typedef __bf16 bf16x4v __attribute__((ext_vector_type(4)));
typedef float f32x4 __attribute__((ext_vector_type(4)));
typedef unsigned u32x2 __attribute__((ext_vector_type(2)));
typedef unsigned u32x4 __attribute__((ext_vector_type(4)));

#define DEV __device__ __forceinline__

#if __has_builtin(__builtin_amdgcn_exp2f)
#define EXP2(x) __builtin_amdgcn_exp2f(x)
#else
#define EXP2(x) exp2f(x)
#endif

DEV __bf16 f2bf(float f) { return (__bf16)f; }

DEV void gload16(const void* g, void* l) {
  __builtin_amdgcn_global_load_lds(
      (const __attribute__((address_space(1))) unsigned int*)(uintptr_t)g,
      (__attribute__((address_space(3))) unsigned int*)(uintptr_t)l,
      16, 0, 0);
}

#define MFMA16(a, b, c) __builtin_amdgcn_mfma_f32_16x16x32_bf16((a), (b), (c), 0, 0, 0)

// ---------------------------------------------------------------- convert x
__global__ __launch_bounds__(256) void f2bf_vec4(const float4* __restrict__ in,
                                                 bf16x4v* __restrict__ out, int n4) {
  int i = blockIdx.x * blockDim.x + threadIdx.x;
  int stride = gridDim.x * blockDim.x;
  for (; i < n4; i += stride) {
    float4 v = in[i];
    bf16x4v o = { f2bf(v.x), f2bf(v.y), f2bf(v.z), f2bf(v.w) };
    out[i] = o;
  }
}

// ------------------------------------------------------------- pack mask bits
__global__ __launch_bounds__(256) void pack_mask(const unsigned char* __restrict__ mask,
                                                 unsigned* __restrict__ pm) {
  int t = threadIdx.x;
  int b = t >> 6, tile = (t >> 1) & 31, half = t & 1;
  unsigned bits = 0;
  for (int j = 0; j < 32; ++j)
    if (mask[b * 2048 + tile * 64 + half * 32 + j]) bits |= (1u << j);
  pm[b * 64 + tile * 2 + half] = bits;
}

// ----------------------------------------------------- pack qkv bias (scaled)
__global__ __launch_bounds__(256) void pack_bias(const float* __restrict__ bq,
                                                 const float* __restrict__ bk,
                                                 const float* __restrict__ bv,
                                                 float* __restrict__ pb, float qs) {
  int i = blockIdx.x * 256 + threadIdx.x;
  float v = (i < 1024) ? bq[i] * qs : (i < 2048) ? bk[i - 1024] : bv[i - 2048];
  pb[i] = v;
}

// ----------------------------------- all 4 W (K,N) f32 -> W^T (N,K) bf16, fused
__global__ __launch_bounds__(256) void transpose_w4(const float* __restrict__ w0,
                                                    const float* __restrict__ w1,
                                                    const float* __restrict__ w2,
                                                    const float* __restrict__ w3,
                                                    __bf16* __restrict__ dstb, float qs) {
  __shared__ float tile[32][33];
  const int which = blockIdx.z;
  const float* src = which == 0 ? w0 : which == 1 ? w1 : which == 2 ? w2 : w3;
  const float scale = (which == 0) ? qs : 1.0f;
  __bf16* dst = dstb + (size_t)which * 1024 * 1024;
  const int tx = threadIdx.x & 31;
  const int ty = threadIdx.x >> 5;
  const int x0 = blockIdx.x * 32;
  const int y0 = blockIdx.y * 32;
#pragma unroll
  for (int j = 0; j < 4; ++j)
    tile[ty + j * 8][tx] = src[(size_t)(y0 + ty + j * 8) * 1024 + x0 + tx];
  __syncthreads();
#pragma unroll
  for (int j = 0; j < 4; ++j)
    dst[(size_t)(x0 + ty + j * 8) * 1024 + y0 + tx] = f2bf(tile[tx][ty + j * 8] * scale);
}

// ------------------------------------------------------------ 256x128 GEMM v3
// 8 waves (4M x 2N), BK=64, 3-buffer LDS ring (48KB each, 144KB dynamic),
// prefetch distance 2 K-tiles, counted vmcnt(8) once per K-tile, 4 phases/K-tile,
// 1 raw s_barrier per phase, XOR chunk-swizzle staging/reads, setprio on MFMA.
// mode 2: fp32 row-major to o0 (N=1024). mode 3: fused QKV (N=3072):
//   seg 0 -> q head-split, 1 -> k head-split, 2 -> v (bh,hd,s) slot-permuted.
__global__ __launch_bounds__(512, 2) void gemm256(const __bf16* __restrict__ A,
                                                  const __bf16* __restrict__ Bt,
                                                  const float* __restrict__ bias,
                                                  void* __restrict__ o0, void* __restrict__ o1,
                                                  void* __restrict__ o2,
                                                  int nbn, int mode) {
  extern __shared__ __align__(16) char smem_raw[];
  __bf16* S = (__bf16*)smem_raw;          // 3 bufs x (A 16384 + B 8192) elems
  constexpr int K = 1024;
  const int t = threadIdx.x;
  const int lane = t & 63, w = t >> 6;
  const int g = lane >> 4, c = lane & 15;
  const int sw = c & 7;
  const int wm = w & 3, wn = w >> 2;      // 4 m-quarters x 2 n-halves
  const int bid = blockIdx.x;
  const int xcd = bid & 7, j0 = bid >> 3;
  const int mb = xcd * 4 + j0 / nbn;      // XCD-pinned m-stripe
  const int nb = j0 % nbn;
  const int m0 = mb << 8;
  const int n0 = nb << 7;

  // bias preload; drain before staging so in-loop vmcnt counts only stage loads
  float bb4[4];
#pragma unroll
  for (int jj = 0; jj < 4; ++jj) bb4[jj] = bias[n0 + wn * 64 + jj * 16 + c];
  asm volatile("" :: "v"(bb4[0]), "v"(bb4[1]), "v"(bb4[2]), "v"(bb4[3]) : "memory");

  f32x4 acc[4][4];
#pragma unroll
  for (int i = 0; i < 4; ++i)
#pragma unroll
    for (int jj = 0; jj < 4; ++jj) acc[i][jj] = f32x4{0.f, 0.f, 0.f, 0.f};

  // staging: A half h = 128 rows (2 loads/thread); B half h = 64 rows (1 load)
  auto stA = [&](int bufe, int k0, int h) {
#pragma unroll
    for (int r2 = 0; r2 < 2; ++r2) {
      int slot = r2 * 512 + t;
      int row = slot >> 3;
      int gch = (slot & 7) ^ (row & 7);
      gload16(&A[(size_t)(m0 + h * 128 + row) * K + k0 + gch * 8],
              &S[bufe + h * 8192 + slot * 8]);
    }
  };
  auto stB = [&](int bufe, int k0, int h) {
    int row = t >> 3;
    int gch = (t & 7) ^ (row & 7);
    gload16(&Bt[(size_t)(n0 + h * 64 + row) * K + k0 + gch * 8],
            &S[bufe + 16384 + h * 4096 + t * 8]);
  };

  asm volatile("s_waitcnt vmcnt(0)" ::: "memory");      // bias drained
  // prologue: stage tiles 0 and 1 fully (12 loads/thread in flight)
  stA(0, 0, 0); stA(0, 0, 1); stB(0, 0, 0); stB(0, 0, 1);
  stA(24576, 64, 0); stA(24576, 64, 1); stB(24576, 64, 0); stB(24576, 64, 1);

  const int arow = wm * 64 + c;
  const int brow = wn * 64 + c;

#pragma unroll 1
  for (int kt = 0; kt < 16; ++kt) {
    const int cb = (kt % 3) * 24576;
    const int pb2 = ((kt + 2) % 3) * 24576;
    const int k0p = (kt + 2) << 6;
    const __bf16* Ab = S + cb;
    const __bf16* Bb = S + cb + 16384;
    bf16x8 af[2][2], b01[2][2], b23[2][2];

    // ---- phase 0: stage A0(kt+2); wait tile kt; quadrant (m01 x n01) ----
    if (kt < 14) {
      stA(pb2, k0p, 0);
      asm volatile("s_waitcnt vmcnt(8)" ::: "memory");  // kt's 6 loads landed
    } else if (kt == 14) {
      asm volatile("s_waitcnt vmcnt(6)" ::: "memory");
    } else {
      asm volatile("s_waitcnt vmcnt(0)" ::: "memory");
    }
    __builtin_amdgcn_s_barrier();
#pragma unroll
    for (int i = 0; i < 2; ++i)
#pragma unroll
      for (int kk = 0; kk < 2; ++kk)
        af[i][kk] = *(const bf16x8*)&Ab[(arow + i * 16) * 64 + (((kk * 4 + g) ^ sw) << 3)];
#pragma unroll
    for (int jn = 0; jn < 2; ++jn)
#pragma unroll
      for (int kk = 0; kk < 2; ++kk)
        b01[jn][kk] = *(const bf16x8*)&Bb[(brow + jn * 16) * 64 + (((kk * 4 + g) ^ sw) << 3)];
    __builtin_amdgcn_s_setprio(1);
#pragma unroll
    for (int kk = 0; kk < 2; ++kk)
#pragma unroll
      for (int i = 0; i < 2; ++i)
#pragma unroll
        for (int jn = 0; jn < 2; ++jn)
          acc[i][jn] = MFMA16(af[i][kk], b01[jn][kk], acc[i][jn]);
    __builtin_amdgcn_s_setprio(0);

    // ---- phase 1: stage A1(kt+2); quadrant (m01 x n23) ----
    if (kt < 14) stA(pb2, k0p, 1);
    asm volatile("" ::: "memory");
    __builtin_amdgcn_s_barrier();
#pragma unroll
    for (int jn = 0; jn < 2; ++jn)
#pragma unroll
      for (int kk = 0; kk < 2; ++kk)
        b23[jn][kk] = *(const bf16x8*)&Bb[(brow + (jn + 2) * 16) * 64 + (((kk * 4 + g) ^ sw) << 3)];
    __builtin_amdgcn_s_setprio(1);
#pragma unroll
    for (int kk = 0; kk < 2; ++kk)
#pragma unroll
      for (int i = 0; i < 2; ++i)
#pragma unroll
        for (int jn = 0; jn < 2; ++jn)
          acc[i][jn + 2] = MFMA16(af[i][kk], b23[jn][kk], acc[i][jn + 2]);
    __builtin_amdgcn_s_setprio(0);

    // ---- phase 2: stage B0(kt+2); quadrant (m23 x n01) ----
    if (kt < 14) stB(pb2, k0p, 0);
    asm volatile("" ::: "memory");
    __builtin_amdgcn_s_barrier();
#pragma unroll
    for (int i = 0; i < 2; ++i)
#pragma unroll
      for (int kk = 0; kk < 2; ++kk)
        af[i][kk] = *(const bf16x8*)&Ab[(arow + (i + 2) * 16) * 64 + (((kk * 4 + g) ^ sw) << 3)];
    __builtin_amdgcn_s_setprio(1);
#pragma unroll
    for (int kk = 0; kk < 2; ++kk)
#pragma unroll
      for (int i = 0; i < 2; ++i)
#pragma unroll
        for (int jn = 0; jn < 2; ++jn)
          acc[i + 2][jn] = MFMA16(af[i][kk], b01[jn][kk], acc[i + 2][jn]);
    __builtin_amdgcn_s_setprio(0);

    // ---- phase 3: stage B1(kt+2); quadrant (m23 x n23), no new reads ----
    if (kt < 14) stB(pb2, k0p, 1);
    asm volatile("" ::: "memory");
    __builtin_amdgcn_s_barrier();
    __builtin_amdgcn_s_setprio(1);
#pragma unroll
    for (int kk = 0; kk < 2; ++kk)
#pragma unroll
      for (int i = 0; i < 2; ++i)
#pragma unroll
        for (int jn = 0; jn < 2; ++jn)
          acc[i + 2][jn + 2] = MFMA16(af[i][kk], b23[jn][kk], acc[i + 2][jn + 2]);
    __builtin_amdgcn_s_setprio(0);
  }

  if (mode == 2) {
    // direct fp32 stores
#pragma unroll
    for (int i = 0; i < 4; ++i) {
      const int rowb = m0 + wm * 64 + i * 16 + g * 4;
#pragma unroll
      for (int jj = 0; jj < 4; ++jj) {
        const int col = n0 + wn * 64 + jj * 16 + c;
#pragma unroll
        for (int r = 0; r < 4; ++r)
          ((float*)o0)[(size_t)(rowb + r) * 1024 + col] = acc[i][jj][r] + bb4[jj];
      }
    }
    return;
  }

  // mode 3: LDS-bounce epilogue, one pass per head (tile = 2 heads of 64 cols)
  const int seg = n0 >> 10;
  const int hb = (n0 & 1023) >> 6;
  const int bidx = m0 >> 11;
  const int s0g = m0 & 2047;
  unsigned short* LB = (unsigned short*)S;

#pragma unroll
  for (int hh = 0; hh < 2; ++hh) {
    __syncthreads();
    if (wn == hh) {
#pragma unroll
      for (int i = 0; i < 4; ++i) {
        const int rl = wm * 64 + i * 16 + g * 4;
#pragma unroll
        for (int jj = 0; jj < 4; ++jj) {
          const int col = jj * 16 + c;
#pragma unroll
          for (int r = 0; r < 4; ++r) {
            const int row = rl + r;                      // 0..255 local
            __bf16 v = f2bf(acc[i][jj][r] + bb4[jj]);
            if (seg < 2) {
              LB[row * 72 + col] = __builtin_bit_cast(unsigned short, v);
            } else {
              // slot-permute (s[2]->sp[3], s[3]->sp[4], s[4]->sp[2]); local-safe
              int spl = (row & ~0x1C) | ((row & 0x0C) << 1) | ((row & 0x10) >> 2);
              LB[col * 264 + spl] = __builtin_bit_cast(unsigned short, v);
            }
          }
        }
      }
    }
    __syncthreads();
    if (seg < 2) {
      __bf16* dst = (__bf16*)(seg == 0 ? o0 : o1);
      const size_t hbase = ((size_t)(bidx * 16 + hb + hh) * 2048 + s0g) * 64;
#pragma unroll
      for (int s4 = 0; s4 < 4; ++s4) {
        int row = s4 * 64 + (t >> 3);
        int hd0 = (t & 7) * 8;
        bf16x8 v = *(const bf16x8*)&LB[row * 72 + hd0];
        *(bf16x8*)&dst[hbase + (size_t)row * 64 + hd0] = v;
      }
    } else {
      __bf16* dst = (__bf16*)o2;
#pragma unroll
      for (int p = 0; p < 4; ++p) {
        int hd = p * 16 + (t >> 5);
        int sl = (t & 31) * 8;
        bf16x8 v = *(const bf16x8*)&LB[hd * 264 + sl];
        *(bf16x8*)&dst[((size_t)(bidx * 16 + hb + hh) * 64 + hd) * 2048 + s0g + sl] = v;
      }
    }
  }
}

// ------------------------------------------------------------ flash attention v6
// q,k: (BH,S,64) bf16 (q pre-scaled by 0.125*log2e); vt: (BH,64,S) bf16 SLOT-PERMUTED
__global__ __launch_bounds__(256, 4) void attn_kernel(const __bf16* __restrict__ q,
                                                      const __bf16* __restrict__ k,
                                                      const __bf16* __restrict__ vt,
                                                      const unsigned* __restrict__ pm,
                                                      __bf16* __restrict__ outp) {
  const int bid = blockIdx.x;
  const int xcd = bid & 7, j = bid >> 3;
  const int bh = xcd * 8 + (j & 7), qb = j >> 3;
  const int b = bh >> 4, h = bh & 15;
  const int t = threadIdx.x, lane = t & 63, w = t >> 6;
  const int g = lane >> 4, c = lane & 15;
  const int sw = c & 7;

  __shared__ alignas(16) __bf16 S[12288];
  __bf16* Vs = S + 8192;

  const size_t kbase = (size_t)bh * (2048 * 64);
  const size_t vbase = (size_t)bh * (64 * 2048);
  const int q0 = qb * 128 + w * 32;

  unsigned mword = pm[b * 64 + lane];

  bf16x8 qf[2][2];
#pragma unroll
  for (int i = 0; i < 2; ++i)
#pragma unroll
    for (int m = 0; m < 2; ++m)
      qf[i][m] = *(const bf16x8*)&q[kbase + (size_t)(q0 + i * 16 + c) * 64 + m * 32 + g * 8];
  asm volatile("" :: "v"(qf[0][0]), "v"(qf[0][1]), "v"(qf[1][0]), "v"(qf[1][1]),
                     "v"(mword) : "memory");

  f32x4 acc[2][4];
  f32x4 lacc[2];
#pragma unroll
  for (int i = 0; i < 2; ++i) {
    lacc[i] = f32x4{0.f, 0.f, 0.f, 0.f};
#pragma unroll
    for (int n = 0; n < 4; ++n) acc[i][n] = f32x4{0.f, 0.f, 0.f, 0.f};
  }

  const bf16x8 ones = { (__bf16)1.f, (__bf16)1.f, (__bf16)1.f, (__bf16)1.f,
                        (__bf16)1.f, (__bf16)1.f, (__bf16)1.f, (__bf16)1.f };

  auto stageK = [&](int bb, int kv0) {
#pragma unroll
    for (int r2 = 0; r2 < 2; ++r2) {
      int slot = r2 * 256 + t;
      int row = slot >> 3, ch = slot & 7;
      int gch = ch ^ (row & 7);
      gload16(&k[kbase + (size_t)(kv0 + row) * 64 + gch * 8], &S[bb * 4096 + slot * 8]);
    }
  };
  auto stageV = [&](int kv0) {
#pragma unroll
    for (int r2 = 0; r2 < 2; ++r2) {
      int slot = r2 * 256 + t;
      int row = slot >> 3, ch = slot & 7;
      int gch = ch ^ (row & 7);
      gload16(&vt[vbase + (size_t)row * 2048 + kv0 + gch * 8], &Vs[slot * 8]);
    }
  };

  stageK(0, 0);
  stageV(0);

#pragma unroll 1
  for (int kv = 0; kv < 32; ++kv) {
    const int bb = kv & 1;
    const int kv0 = kv << 6;
    if (kv < 31) {
      stageK(bb ^ 1, kv0 + 64);
      asm volatile("s_waitcnt vmcnt(2)" ::: "memory");
    } else {
      asm volatile("s_waitcnt vmcnt(0)" ::: "memory");
    }
    __builtin_amdgcn_s_barrier();

    const __bf16* ksb = S + (bb << 12);
    unsigned mwlo = __builtin_amdgcn_readlane(mword, 2 * kv);
    unsigned mwhi = __builtin_amdgcn_readlane(mword, 2 * kv + 1);

    __builtin_amdgcn_s_setprio(1);
    f32x4 sc[2][4];
#pragma unroll
    for (int n = 0; n < 4; ++n) {
      bf16x8 kf0 = *(const bf16x8*)&ksb[(n * 16 + c) * 64 + (((0 + g) ^ sw) << 3)];
      bf16x8 kf1 = *(const bf16x8*)&ksb[(n * 16 + c) * 64 + (((4 + g) ^ sw) << 3)];
#pragma unroll
      for (int i = 0; i < 2; ++i) {
        f32x4 z = f32x4{0.f, 0.f, 0.f, 0.f};
        z = MFMA16(kf0, qf[i][0], z);
        z = MFMA16(kf1, qf[i][1], z);
        sc[i][n] = z;
      }
    }
    __builtin_amdgcn_sched_barrier(0);

    u32x4 pf0[2];
    if (mwlo) {
#pragma unroll
      for (int n = 0; n < 2; ++n)
#pragma unroll
        for (int r = 0; r < 4; ++r)
          if ((mwlo >> (n * 16 + g * 4 + r)) & 1u) { sc[0][n][r] = -1e30f; sc[1][n][r] = -1e30f; }
    }
#pragma unroll
    for (int i = 0; i < 2; ++i) {
      float p0 = EXP2(sc[i][0][0]), p1 = EXP2(sc[i][0][1]);
      float p2 = EXP2(sc[i][0][2]), p3 = EXP2(sc[i][0][3]);
      float p4 = EXP2(sc[i][1][0]), p5 = EXP2(sc[i][1][1]);
      float p6 = EXP2(sc[i][1][2]), p7 = EXP2(sc[i][1][3]);
      unsigned w0, w1, w2, w3;
      asm("v_cvt_pk_bf16_f32 %0, %1, %2" : "=v"(w0) : "v"(p0), "v"(p1));
      asm("v_cvt_pk_bf16_f32 %0, %1, %2" : "=v"(w1) : "v"(p2), "v"(p3));
      asm("v_cvt_pk_bf16_f32 %0, %1, %2" : "=v"(w2) : "v"(p4), "v"(p5));
      asm("v_cvt_pk_bf16_f32 %0, %1, %2" : "=v"(w3) : "v"(p6), "v"(p7));
      pf0[i] = u32x4{w0, w1, w2, w3};
    }

#pragma unroll
    for (int n = 0; n < 4; ++n) {
      bf16x8 vf0 = *(const bf16x8*)&Vs[(n * 16 + c) * 64 + (((0 + g) ^ sw) << 3)];
#pragma unroll
      for (int i = 0; i < 2; ++i)
        acc[i][n] = MFMA16(vf0, __builtin_bit_cast(bf16x8, pf0[i]), acc[i][n]);
    }
#pragma unroll
    for (int i = 0; i < 2; ++i)
      lacc[i] = MFMA16(ones, __builtin_bit_cast(bf16x8, pf0[i]), lacc[i]);
    __builtin_amdgcn_sched_barrier(0);

    u32x4 pf1[2];
    if (mwhi) {
#pragma unroll
      for (int n = 2; n < 4; ++n)
#pragma unroll
        for (int r = 0; r < 4; ++r)
          if ((mwhi >> ((n - 2) * 16 + g * 4 + r)) & 1u) { sc[0][n][r] = -1e30f; sc[1][n][r] = -1e30f; }
    }
#pragma unroll
    for (int i = 0; i < 2; ++i) {
      float p0 = EXP2(sc[i][2][0]), p1 = EXP2(sc[i][2][1]);
      float p2 = EXP2(sc[i][2][2]), p3 = EXP2(sc[i][2][3]);
      float p4 = EXP2(sc[i][3][0]), p5 = EXP2(sc[i][3][1]);
      float p6 = EXP2(sc[i][3][2]), p7 = EXP2(sc[i][3][3]);
      unsigned w0, w1, w2, w3;
      asm("v_cvt_pk_bf16_f32 %0, %1, %2" : "=v"(w0) : "v"(p0), "v"(p1));
      asm("v_cvt_pk_bf16_f32 %0, %1, %2" : "=v"(w1) : "v"(p2), "v"(p3));
      asm("v_cvt_pk_bf16_f32 %0, %1, %2" : "=v"(w2) : "v"(p4), "v"(p5));
      asm("v_cvt_pk_bf16_f32 %0, %1, %2" : "=v"(w3) : "v"(p6), "v"(p7));
      pf1[i] = u32x4{w0, w1, w2, w3};
    }

#pragma unroll
    for (int n = 0; n < 4; ++n) {
      bf16x8 vf1 = *(const bf16x8*)&Vs[(n * 16 + c) * 64 + (((4 + g) ^ sw) << 3)];
#pragma unroll
      for (int i = 0; i < 2; ++i)
        acc[i][n] = MFMA16(vf1, __builtin_bit_cast(bf16x8, pf1[i]), acc[i][n]);
    }
#pragma unroll
    for (int i = 0; i < 2; ++i)
      lacc[i] = MFMA16(ones, __builtin_bit_cast(bf16x8, pf1[i]), lacc[i]);
    __builtin_amdgcn_s_setprio(0);

    __builtin_amdgcn_s_barrier();
    if (kv < 31) stageV(kv0 + 64);
  }

  float linv[2];
#pragma unroll
  for (int i = 0; i < 2; ++i) linv[i] = 1.0f / fmaxf(lacc[i][0], 1e-30f);

  __bf16* ot = S + w * 2176;
#pragma unroll
  for (int i = 0; i < 2; ++i)
#pragma unroll
    for (int n = 0; n < 4; ++n) {
      float a0 = acc[i][n][0] * linv[i], a1 = acc[i][n][1] * linv[i];
      float a2 = acc[i][n][2] * linv[i], a3 = acc[i][n][3] * linv[i];
      unsigned w0, w1;
      asm("v_cvt_pk_bf16_f32 %0, %1, %2" : "=v"(w0) : "v"(a0), "v"(a1));
      asm("v_cvt_pk_bf16_f32 %0, %1, %2" : "=v"(w1) : "v"(a2), "v"(a3));
      *(u32x2*)&ot[(i * 16 + c) * 68 + n * 16 + g * 4] = u32x2{w0, w1};
    }
  asm volatile("s_waitcnt lgkmcnt(0)" ::: "memory");
  __builtin_amdgcn_sched_barrier(0);
#pragma unroll
  for (int ps = 0; ps < 4; ++ps) {
    int rr = ps * 8 + (lane >> 3);
    bf16x8 ov = *(const bf16x8*)&ot[rr * 68 + (lane & 7) * 8];
    *(bf16x8*)&outp[((size_t)b * 2048 + q0 + rr) * 1024 + h * 64 + (lane & 7) * 8] = ov;
  }
}

// ----------------------------------------------------------------- launcher
extern "C" void kernel_launch(void* const* d_in, const int* in_sizes, int n_in,
                              void* d_out, int out_size, void* d_ws, size_t ws_size,
                              hipStream_t stream) {
  (void)in_sizes; (void)n_in; (void)out_size; (void)ws_size;
  const float* x  = (const float*)d_in[0];
  const unsigned char* mask = (const unsigned char*)d_in[1];
  const float* Wq = (const float*)d_in[2];
  const float* bq = (const float*)d_in[3];
  const float* Wk = (const float*)d_in[4];
  const float* bk = (const float*)d_in[5];
  const float* Wv = (const float*)d_in[6];
  const float* bv = (const float*)d_in[7];
  const float* Wo = (const float*)d_in[8];
  const float* bo = (const float*)d_in[9];
  float* out = (float*)d_out;

  char* ws = (char*)d_ws;
  const size_t SZ = (size_t)8192 * 1024 * 2;
  const size_t WSZ = (size_t)1024 * 1024 * 2;
  __bf16* xb  = (__bf16*)(ws);
  __bf16* qb  = (__bf16*)(ws + SZ);
  __bf16* kb  = (__bf16*)(ws + 2 * SZ);
  __bf16* vtb = (__bf16*)(ws + 3 * SZ);
  __bf16* wtq = (__bf16*)(ws + 4 * SZ);            // wtq,wtk,wtv,wto contiguous
  __bf16* wto = (__bf16*)(ws + 4 * SZ + 3 * WSZ);
  unsigned* pmask = (unsigned*)(ws + 4 * SZ + 4 * WSZ);
  float* pb = (float*)(ws + 4 * SZ + 4 * WSZ + 4096);

  const float QSCALE = 0.125f * 1.44269504f;
  const int LDSB = 147456;                          // 3 x 48KB ring

  f2bf_vec4<<<2048, 256, 0, stream>>>((const float4*)x, (bf16x4v*)xb, 8192 * 1024 / 4);
  pack_mask<<<1, 256, 0, stream>>>(mask, pmask);
  pack_bias<<<12, 256, 0, stream>>>(bq, bk, bv, pb, QSCALE);
  transpose_w4<<<dim3(32, 32, 4), 256, 0, stream>>>(Wq, Wk, Wv, Wo, wtq, QSCALE);
  // fused QKV projection (M=8192, N=3072): 32 x 24 = 768 blocks = 3 exact rounds
  gemm256<<<dim3(768), 512, LDSB, stream>>>(xb, wtq, pb, qb, kb, vtb, 24, 3);
  attn_kernel<<<dim3(1024), 256, 0, stream>>>(qb, kb, vtb, pmask, xb);
  // output projection (N=1024): 32 x 8 = 256 blocks = 1 exact round
  gemm256<<<dim3(256), 512, LDSB, stream>>>(xb, wto, bo, out, nullptr, nullptr, 8, 2);
}

// Round 9
// 173.811 us; speedup vs baseline: 1.0593x; 1.0593x over previous
//
#include <hip/hip_runtime.h>
#include <cstdint>

// MHA fwd: B=4, S=2048, D=1024, H=16, HD=64. fp32 in/out.
// Round 9: GEMM reverted to m97-exact structure (128x128, BK=64, SINGLE-buffered
// 32KB LDS, plain __syncthreads drain, 4 blocks/CU block-TLP covers the drain)
// + XOR chunk-swizzle (conflict-free) + m-fast XCD grid map. Attn v6 unchanged.

typedef __bf16 bf16x8 __attribute__((ext_vector_type(8)));
typedef __bf16 bf16x4v __attribute__((ext_vector_type(4)));
typedef float f32x4 __attribute__((ext_vector_type(4)));
typedef unsigned u32x2 __attribute__((ext_vector_type(2)));
typedef unsigned u32x4 __attribute__((ext_vector_type(4)));

#define DEV __device__ __forceinline__

#if __has_builtin(__builtin_amdgcn_exp2f)
#define EXP2(x) __builtin_amdgcn_exp2f(x)
#else
#define EXP2(x) exp2f(x)
#endif

DEV __bf16 f2bf(float f) { return (__bf16)f; }

DEV void gload16(const void* g, void* l) {
  __builtin_amdgcn_global_load_lds(
      (const __attribute__((address_space(1))) unsigned int*)(uintptr_t)g,
      (__attribute__((address_space(3))) unsigned int*)(uintptr_t)l,
      16, 0, 0);
}

#define MFMA16(a, b, c) __builtin_amdgcn_mfma_f32_16x16x32_bf16((a), (b), (c), 0, 0, 0)

// ---------------------------------------------------------------- convert x
__global__ __launch_bounds__(256) void f2bf_vec4(const float4* __restrict__ in,
                                                 bf16x4v* __restrict__ out, int n4) {
  int i = blockIdx.x * blockDim.x + threadIdx.x;
  int stride = gridDim.x * blockDim.x;
  for (; i < n4; i += stride) {
    float4 v = in[i];
    bf16x4v o = { f2bf(v.x), f2bf(v.y), f2bf(v.z), f2bf(v.w) };
    out[i] = o;
  }
}

// ------------------------------------------------------------- pack mask bits
__global__ __launch_bounds__(256) void pack_mask(const unsigned char* __restrict__ mask,
                                                 unsigned* __restrict__ pm) {
  int t = threadIdx.x;
  int b = t >> 6, tile = (t >> 1) & 31, half = t & 1;
  unsigned bits = 0;
  for (int j = 0; j < 32; ++j)
    if (mask[b * 2048 + tile * 64 + half * 32 + j]) bits |= (1u << j);
  pm[b * 64 + tile * 2 + half] = bits;
}

// ----------------------------------------------------- pack qkv bias (scaled)
__global__ __launch_bounds__(256) void pack_bias(const float* __restrict__ bq,
                                                 const float* __restrict__ bk,
                                                 const float* __restrict__ bv,
                                                 float* __restrict__ pb, float qs) {
  int i = blockIdx.x * 256 + threadIdx.x;
  float v = (i < 1024) ? bq[i] * qs : (i < 2048) ? bk[i - 1024] : bv[i - 2048];
  pb[i] = v;
}

// ----------------------------------- all 4 W (K,N) f32 -> W^T (N,K) bf16, fused
__global__ __launch_bounds__(256) void transpose_w4(const float* __restrict__ w0,
                                                    const float* __restrict__ w1,
                                                    const float* __restrict__ w2,
                                                    const float* __restrict__ w3,
                                                    __bf16* __restrict__ dstb, float qs) {
  __shared__ float tile[32][33];
  const int which = blockIdx.z;
  const float* src = which == 0 ? w0 : which == 1 ? w1 : which == 2 ? w2 : w3;
  const float scale = (which == 0) ? qs : 1.0f;
  __bf16* dst = dstb + (size_t)which * 1024 * 1024;
  const int tx = threadIdx.x & 31;
  const int ty = threadIdx.x >> 5;
  const int x0 = blockIdx.x * 32;
  const int y0 = blockIdx.y * 32;
#pragma unroll
  for (int j = 0; j < 4; ++j)
    tile[ty + j * 8][tx] = src[(size_t)(y0 + ty + j * 8) * 1024 + x0 + tx];
  __syncthreads();
#pragma unroll
  for (int j = 0; j < 4; ++j)
    dst[(size_t)(x0 + ty + j * 8) * 1024 + y0 + tx] = f2bf(tile[tx][ty + j * 8] * scale);
}

// --------------------------------------------------------------- 128x128 GEMM v5
// m97-exact: single-buffered 32KB LDS, stage -> __syncthreads -> MFMA ->
// __syncthreads; XOR chunk-swizzled staging/reads (conflict-free); 4 blocks/CU.
// 1-D grid, XCD-aware m-fast swizzle: m0=((bid&7)*8+(j&7))*128, n0=(j>>3)*128.
// mode 2: fp32 row-major out to o0 (N=1024)
// mode 3: fused QKV (N=3072): seg 0 -> q head-split, 1 -> k head-split,
//         2 -> v transposed (bh,hd,s) with in-tile key-slot permutation.
__global__ __launch_bounds__(256, 4) void gemm128(const __bf16* __restrict__ A,
                                                  const __bf16* __restrict__ Bt,
                                                  const float* __restrict__ bias,
                                                  void* __restrict__ o0, void* __restrict__ o1,
                                                  void* __restrict__ o2, int mode) {
  constexpr int K = 1024;
  __shared__ alignas(16) __bf16 S[16384];        // As[8192] | Bs[8192] = 32KB
  __bf16* As_ = S;
  __bf16* Bs_ = S + 8192;
  const int t = threadIdx.x;
  const int lane = t & 63, w = t >> 6;
  const int g = lane >> 4, c = lane & 15;
  const int sw = c & 7;
  const int wm = w & 1, wn = w >> 1;
  const int bid = blockIdx.x;
  const int j = bid >> 3;
  const int m0 = (((bid & 7) << 3) + (j & 7)) << 7;
  const int n0 = (j >> 3) << 7;

  float bb4[4];
#pragma unroll
  for (int jj = 0; jj < 4; ++jj) bb4[jj] = bias[n0 + wn * 64 + jj * 16 + c];

  f32x4 acc[4][4];
#pragma unroll
  for (int i = 0; i < 4; ++i)
#pragma unroll
    for (int jj = 0; jj < 4; ++jj) acc[i][jj] = f32x4{0.f, 0.f, 0.f, 0.f};

#pragma unroll 1
  for (int kt = 0; kt < 16; ++kt) {
    const int k0 = kt << 6;
#pragma unroll
    for (int i = 0; i < 4; ++i) {
      int slot = i * 256 + t;                    // 128 rows x 8 chunks
      int row = slot >> 3;
      int gch = (slot & 7) ^ (row & 7);          // pre-swizzled global source
      gload16(&A[(size_t)(m0 + row) * K + k0 + gch * 8], &As_[slot * 8]);
      gload16(&Bt[(size_t)(n0 + row) * K + k0 + gch * 8], &Bs_[slot * 8]);
    }
    __syncthreads();                             // vmcnt(0)+barrier (compiler)
#pragma unroll
    for (int kk = 0; kk < 2; ++kk) {
      bf16x8 af[4], bfr[4];
#pragma unroll
      for (int i = 0; i < 4; ++i) {
        af[i]  = *(const bf16x8*)&As_[(wm * 64 + i * 16 + c) * 64 + (((kk * 4 + g) ^ sw) << 3)];
        bfr[i] = *(const bf16x8*)&Bs_[(wn * 64 + i * 16 + c) * 64 + (((kk * 4 + g) ^ sw) << 3)];
      }
#pragma unroll
      for (int i = 0; i < 4; ++i)
#pragma unroll
        for (int jj = 0; jj < 4; ++jj)
          acc[i][jj] = MFMA16(af[i], bfr[jj], acc[i][jj]);
    }
    __syncthreads();                             // buffer free for next stage
  }

  const int bidx = m0 >> 11;
  const int s0g = m0 & 2047;

  if (mode == 2) {
#pragma unroll
    for (int i = 0; i < 4; ++i) {
      const int rowb = m0 + wm * 64 + i * 16 + g * 4;
#pragma unroll
      for (int jj = 0; jj < 4; ++jj) {
        const int col = n0 + wn * 64 + jj * 16 + c;
#pragma unroll
        for (int r = 0; r < 4; ++r)
          ((float*)o0)[(size_t)(rowb + r) * 1024 + col] = acc[i][jj][r] + bb4[jj];
      }
    }
    return;
  }

  // mode 3: bounce epilogue, one pass per head-half
  const int seg = n0 >> 10;
  const int hb = (n0 & 1023) >> 6;
  unsigned short* LB = (unsigned short*)S;

#pragma unroll
  for (int hh = 0; hh < 2; ++hh) {
    __syncthreads();
    if (wn == hh) {                              // this wave-pair owns cols [hh*64, hh*64+64)
#pragma unroll
      for (int i = 0; i < 4; ++i) {
        const int rl = wm * 64 + i * 16 + g * 4;
#pragma unroll
        for (int jj = 0; jj < 4; ++jj) {
          const int col = jj * 16 + c;
#pragma unroll
          for (int r = 0; r < 4; ++r) {
            const int row = rl + r;
            __bf16 v = f2bf(acc[i][jj][r] + bb4[jj]);
            if (seg < 2) {
              LB[row * 72 + col] = __builtin_bit_cast(unsigned short, v);
            } else {
              // slot-permute: s[2]->sp[3], s[3]->sp[4], s[4]->sp[2]
              int spl = (row & ~0x1C) | ((row & 0x0C) << 1) | ((row & 0x10) >> 2);
              LB[col * 136 + spl] = __builtin_bit_cast(unsigned short, v);
            }
          }
        }
      }
    }
    __syncthreads();
    if (seg < 2) {
      __bf16* dst = (__bf16*)(seg == 0 ? o0 : o1);
      const size_t hbase = ((size_t)(bidx * 16 + hb + hh) * 2048 + s0g) * 64;
#pragma unroll
      for (int s4 = 0; s4 < 4; ++s4) {
        int row = s4 * 32 + (t >> 3);
        int hd0 = (t & 7) * 8;
        bf16x8 v = *(const bf16x8*)&LB[row * 72 + hd0];
        *(bf16x8*)&dst[hbase + (size_t)row * 64 + hd0] = v;
      }
    } else {
      __bf16* dst = (__bf16*)o2;
      const int hd = t >> 2, q4 = t & 3;
      const size_t vb = ((size_t)(bidx * 16 + hb + hh) * 64 + hd) * 2048 + s0g;
#pragma unroll
      for (int kk = 0; kk < 4; ++kk) {
        int spb = q4 * 32 + kk * 8;
        bf16x8 v = *(const bf16x8*)&LB[hd * 136 + spb];
        *(bf16x8*)&dst[vb + spb] = v;
      }
    }
  }
}

// ------------------------------------------------------------ flash attention v6
// q,k: (BH,S,64) bf16 (q pre-scaled by 0.125*log2e); vt: (BH,64,S) bf16 SLOT-PERMUTED
__global__ __launch_bounds__(256, 4) void attn_kernel(const __bf16* __restrict__ q,
                                                      const __bf16* __restrict__ k,
                                                      const __bf16* __restrict__ vt,
                                                      const unsigned* __restrict__ pm,
                                                      __bf16* __restrict__ outp) {
  const int bid = blockIdx.x;
  const int xcd = bid & 7, j = bid >> 3;
  const int bh = xcd * 8 + (j & 7), qb = j >> 3;
  const int b = bh >> 4, h = bh & 15;
  const int t = threadIdx.x, lane = t & 63, w = t >> 6;
  const int g = lane >> 4, c = lane & 15;
  const int sw = c & 7;

  __shared__ alignas(16) __bf16 S[12288];
  __bf16* Vs = S + 8192;

  const size_t kbase = (size_t)bh * (2048 * 64);
  const size_t vbase = (size_t)bh * (64 * 2048);
  const int q0 = qb * 128 + w * 32;

  unsigned mword = pm[b * 64 + lane];

  bf16x8 qf[2][2];
#pragma unroll
  for (int i = 0; i < 2; ++i)
#pragma unroll
    for (int m = 0; m < 2; ++m)
      qf[i][m] = *(const bf16x8*)&q[kbase + (size_t)(q0 + i * 16 + c) * 64 + m * 32 + g * 8];
  asm volatile("" :: "v"(qf[0][0]), "v"(qf[0][1]), "v"(qf[1][0]), "v"(qf[1][1]),
                     "v"(mword) : "memory");

  f32x4 acc[2][4];
  f32x4 lacc[2];
#pragma unroll
  for (int i = 0; i < 2; ++i) {
    lacc[i] = f32x4{0.f, 0.f, 0.f, 0.f};
#pragma unroll
    for (int n = 0; n < 4; ++n) acc[i][n] = f32x4{0.f, 0.f, 0.f, 0.f};
  }

  const bf16x8 ones = { (__bf16)1.f, (__bf16)1.f, (__bf16)1.f, (__bf16)1.f,
                        (__bf16)1.f, (__bf16)1.f, (__bf16)1.f, (__bf16)1.f };

  auto stageK = [&](int bb, int kv0) {
#pragma unroll
    for (int r2 = 0; r2 < 2; ++r2) {
      int slot = r2 * 256 + t;
      int row = slot >> 3, ch = slot & 7;
      int gch = ch ^ (row & 7);
      gload16(&k[kbase + (size_t)(kv0 + row) * 64 + gch * 8], &S[bb * 4096 + slot * 8]);
    }
  };
  auto stageV = [&](int kv0) {
#pragma unroll
    for (int r2 = 0; r2 < 2; ++r2) {
      int slot = r2 * 256 + t;
      int row = slot >> 3, ch = slot & 7;
      int gch = ch ^ (row & 7);
      gload16(&vt[vbase + (size_t)row * 2048 + kv0 + gch * 8], &Vs[slot * 8]);
    }
  };

  stageK(0, 0);
  stageV(0);

#pragma unroll 1
  for (int kv = 0; kv < 32; ++kv) {
    const int bb = kv & 1;
    const int kv0 = kv << 6;
    if (kv < 31) {
      stageK(bb ^ 1, kv0 + 64);
      asm volatile("s_waitcnt vmcnt(2)" ::: "memory");
    } else {
      asm volatile("s_waitcnt vmcnt(0)" ::: "memory");
    }
    __builtin_amdgcn_s_barrier();

    const __bf16* ksb = S + (bb << 12);
    unsigned mwlo = __builtin_amdgcn_readlane(mword, 2 * kv);
    unsigned mwhi = __builtin_amdgcn_readlane(mword, 2 * kv + 1);

    __builtin_amdgcn_s_setprio(1);
    f32x4 sc[2][4];
#pragma unroll
    for (int n = 0; n < 4; ++n) {
      bf16x8 kf0 = *(const bf16x8*)&ksb[(n * 16 + c) * 64 + (((0 + g) ^ sw) << 3)];
      bf16x8 kf1 = *(const bf16x8*)&ksb[(n * 16 + c) * 64 + (((4 + g) ^ sw) << 3)];
#pragma unroll
      for (int i = 0; i < 2; ++i) {
        f32x4 z = f32x4{0.f, 0.f, 0.f, 0.f};
        z = MFMA16(kf0, qf[i][0], z);
        z = MFMA16(kf1, qf[i][1], z);
        sc[i][n] = z;
      }
    }
    __builtin_amdgcn_sched_barrier(0);

    u32x4 pf0[2];
    if (mwlo) {
#pragma unroll
      for (int n = 0; n < 2; ++n)
#pragma unroll
        for (int r = 0; r < 4; ++r)
          if ((mwlo >> (n * 16 + g * 4 + r)) & 1u) { sc[0][n][r] = -1e30f; sc[1][n][r] = -1e30f; }
    }
#pragma unroll
    for (int i = 0; i < 2; ++i) {
      float p0 = EXP2(sc[i][0][0]), p1 = EXP2(sc[i][0][1]);
      float p2 = EXP2(sc[i][0][2]), p3 = EXP2(sc[i][0][3]);
      float p4 = EXP2(sc[i][1][0]), p5 = EXP2(sc[i][1][1]);
      float p6 = EXP2(sc[i][1][2]), p7 = EXP2(sc[i][1][3]);
      unsigned w0, w1, w2, w3;
      asm("v_cvt_pk_bf16_f32 %0, %1, %2" : "=v"(w0) : "v"(p0), "v"(p1));
      asm("v_cvt_pk_bf16_f32 %0, %1, %2" : "=v"(w1) : "v"(p2), "v"(p3));
      asm("v_cvt_pk_bf16_f32 %0, %1, %2" : "=v"(w2) : "v"(p4), "v"(p5));
      asm("v_cvt_pk_bf16_f32 %0, %1, %2" : "=v"(w3) : "v"(p6), "v"(p7));
      pf0[i] = u32x4{w0, w1, w2, w3};
    }

#pragma unroll
    for (int n = 0; n < 4; ++n) {
      bf16x8 vf0 = *(const bf16x8*)&Vs[(n * 16 + c) * 64 + (((0 + g) ^ sw) << 3)];
#pragma unroll
      for (int i = 0; i < 2; ++i)
        acc[i][n] = MFMA16(vf0, __builtin_bit_cast(bf16x8, pf0[i]), acc[i][n]);
    }
#pragma unroll
    for (int i = 0; i < 2; ++i)
      lacc[i] = MFMA16(ones, __builtin_bit_cast(bf16x8, pf0[i]), lacc[i]);
    __builtin_amdgcn_sched_barrier(0);

    u32x4 pf1[2];
    if (mwhi) {
#pragma unroll
      for (int n = 2; n < 4; ++n)
#pragma unroll
        for (int r = 0; r < 4; ++r)
          if ((mwhi >> ((n - 2) * 16 + g * 4 + r)) & 1u) { sc[0][n][r] = -1e30f; sc[1][n][r] = -1e30f; }
    }
#pragma unroll
    for (int i = 0; i < 2; ++i) {
      float p0 = EXP2(sc[i][2][0]), p1 = EXP2(sc[i][2][1]);
      float p2 = EXP2(sc[i][2][2]), p3 = EXP2(sc[i][2][3]);
      float p4 = EXP2(sc[i][3][0]), p5 = EXP2(sc[i][3][1]);
      float p6 = EXP2(sc[i][3][2]), p7 = EXP2(sc[i][3][3]);
      unsigned w0, w1, w2, w3;
      asm("v_cvt_pk_bf16_f32 %0, %1, %2" : "=v"(w0) : "v"(p0), "v"(p1));
      asm("v_cvt_pk_bf16_f32 %0, %1, %2" : "=v"(w1) : "v"(p2), "v"(p3));
      asm("v_cvt_pk_bf16_f32 %0, %1, %2" : "=v"(w2) : "v"(p4), "v"(p5));
      asm("v_cvt_pk_bf16_f32 %0, %1, %2" : "=v"(w3) : "v"(p6), "v"(p7));
      pf1[i] = u32x4{w0, w1, w2, w3};
    }

#pragma unroll
    for (int n = 0; n < 4; ++n) {
      bf16x8 vf1 = *(const bf16x8*)&Vs[(n * 16 + c) * 64 + (((4 + g) ^ sw) << 3)];
#pragma unroll
      for (int i = 0; i < 2; ++i)
        acc[i][n] = MFMA16(vf1, __builtin_bit_cast(bf16x8, pf1[i]), acc[i][n]);
    }
#pragma unroll
    for (int i = 0; i < 2; ++i)
      lacc[i] = MFMA16(ones, __builtin_bit_cast(bf16x8, pf1[i]), lacc[i]);
    __builtin_amdgcn_s_setprio(0);

    __builtin_amdgcn_s_barrier();
    if (kv < 31) stageV(kv0 + 64);
  }

  float linv[2];
#pragma unroll
  for (int i = 0; i < 2; ++i) linv[i] = 1.0f / fmaxf(lacc[i][0], 1e-30f);

  __bf16* ot = S + w * 2176;
#pragma unroll
  for (int i = 0; i < 2; ++i)
#pragma unroll
    for (int n = 0; n < 4; ++n) {
      float a0 = acc[i][n][0] * linv[i], a1 = acc[i][n][1] * linv[i];
      float a2 = acc[i][n][2] * linv[i], a3 = acc[i][n][3] * linv[i];
      unsigned w0, w1;
      asm("v_cvt_pk_bf16_f32 %0, %1, %2" : "=v"(w0) : "v"(a0), "v"(a1));
      asm("v_cvt_pk_bf16_f32 %0, %1, %2" : "=v"(w1) : "v"(a2), "v"(a3));
      *(u32x2*)&ot[(i * 16 + c) * 68 + n * 16 + g * 4] = u32x2{w0, w1};
    }
  asm volatile("s_waitcnt lgkmcnt(0)" ::: "memory");
  __builtin_amdgcn_sched_barrier(0);
#pragma unroll
  for (int ps = 0; ps < 4; ++ps) {
    int rr = ps * 8 + (lane >> 3);
    bf16x8 ov = *(const bf16x8*)&ot[rr * 68 + (lane & 7) * 8];
    *(bf16x8*)&outp[((size_t)b * 2048 + q0 + rr) * 1024 + h * 64 + (lane & 7) * 8] = ov;
  }
}

// ----------------------------------------------------------------- launcher
extern "C" void kernel_launch(void* const* d_in, const int* in_sizes, int n_in,
                              void* d_out, int out_size, void* d_ws, size_t ws_size,
                              hipStream_t stream) {
  (void)in_sizes; (void)n_in; (void)out_size; (void)ws_size;
  const float* x  = (const float*)d_in[0];
  const unsigned char* mask = (const unsigned char*)d_in[1];
  const float* Wq = (const float*)d_in[2];
  const float* bq = (const float*)d_in[3];
  const float* Wk = (const float*)d_in[4];
  const float* bk = (const float*)d_in[5];
  const float* Wv = (const float*)d_in[6];
  const float* bv = (const float*)d_in[7];
  const float* Wo = (const float*)d_in[8];
  const float* bo = (const float*)d_in[9];
  float* out = (float*)d_out;

  char* ws = (char*)d_ws;
  const size_t SZ = (size_t)8192 * 1024 * 2;
  const size_t WSZ = (size_t)1024 * 1024 * 2;
  __bf16* xb  = (__bf16*)(ws);
  __bf16* qb  = (__bf16*)(ws + SZ);
  __bf16* kb  = (__bf16*)(ws + 2 * SZ);
  __bf16* vtb = (__bf16*)(ws + 3 * SZ);
  __bf16* wtq = (__bf16*)(ws + 4 * SZ);            // wtq,wtk,wtv,wto contiguous
  __bf16* wto = (__bf16*)(ws + 4 * SZ + 3 * WSZ);
  unsigned* pmask = (unsigned*)(ws + 4 * SZ + 4 * WSZ);
  float* pb = (float*)(ws + 4 * SZ + 4 * WSZ + 4096);

  const float QSCALE = 0.125f * 1.44269504f;

  f2bf_vec4<<<2048, 256, 0, stream>>>((const float4*)x, (bf16x4v*)xb, 8192 * 1024 / 4);
  pack_mask<<<1, 256, 0, stream>>>(mask, pmask);
  pack_bias<<<12, 256, 0, stream>>>(bq, bk, bv, pb, QSCALE);
  transpose_w4<<<dim3(32, 32, 4), 256, 0, stream>>>(Wq, Wk, Wv, Wo, wtq, QSCALE);
  // fused QKV projection (N=3072)
  gemm128<<<dim3(1536), 256, 0, stream>>>(xb, wtq, pb, qb, kb, vtb, 3);
  attn_kernel<<<dim3(1024), 256, 0, stream>>>(qb, kb, vtb, pmask, xb);
  // output projection (N=1024)
  gemm128<<<dim3(512), 256, 0, stream>>>(xb, wto, bo, out, nullptr, nullptr, 2);
}